// Round 1
// baseline (2837.933 us; speedup 1.0000x reference)
//
#include <hip/hip_runtime.h>
#include <math.h>

#define NN 262144
#define DD 128
#define KD 261              // 2*128 + 5
#define NODES_PER_BLK 4
#define THREADS 512

__device__ inline float bf2f(unsigned short u) {
    union { float f; unsigned int i; } v; v.i = ((unsigned int)u) << 16; return v.f;
}
__device__ inline unsigned short f2bf(float f) {
    union { float f; unsigned int i; } v; v.f = f;
    unsigned int r = v.i + 0x7fffu + ((v.i >> 16) & 1u);
    return (unsigned short)(r >> 16);
}
__device__ inline float signed_log(float x) {
    float s = (x > 0.f) ? 1.f : ((x < 0.f) ? -1.f : 0.f);
    return s * logf(fabsf(x) + 1e-8f);
}

// upstream[dst[e]] += h[src[e]]  (atomic scatter; up buffer pre-zeroed)
__global__ void scatter_kernel(const float4* __restrict__ h4,
                               const int* __restrict__ src,
                               const int* __restrict__ dst,
                               float* up, int E) {
    int tid = blockIdx.x * blockDim.x + threadIdx.x;
    int e = tid >> 5;
    if (e >= E) return;
    int c = tid & 31;                       // 32 float4 chunks per row of 128
    int s = src[e];
    int d = dst[e];
    float4 v = h4[(size_t)s * 32 + c];
    float* o = up + (size_t)d * DD + c * 4;
    atomicAdd(o + 0, v.x);
    atomicAdd(o + 1, v.y);
    atomicAdd(o + 2, v.z);
    atomicAdd(o + 3, v.w);
}

// Fused: node_input -> silu(@W1+b1) -> @W2+b2 -> +h -> LayerNorm -> out
// `up` aliases `out` (upstream read fully before the final write, per node).
__global__ __launch_bounds__(THREADS) void node_kernel(
    const float* __restrict__ h, const float* up,
    const float* __restrict__ c1, const float* __restrict__ c2,
    const float* __restrict__ c3, const float* __restrict__ c4,
    const float* __restrict__ qn,
    const float* __restrict__ W1, const float* __restrict__ b1,
    const float* __restrict__ W2, const float* __restrict__ b2,
    const float* __restrict__ gamma, const float* __restrict__ beta,
    float* out)
{
    extern __shared__ char smem[];
    unsigned short* sW1 = (unsigned short*)smem;                 // KD*DD bf16   = 66816 B
    float* sW2  = (float*)(smem + KD * DD * 2);                  // DD*DD f32    = 65536 B
    float* sIn  = (float*)(smem + KD * DD * 2 + DD * DD * 4);    // 4 * 264 f32  = 4224 B
    float* sHid = sIn + NODES_PER_BLK * 264;                     // 4 * 128 f32  = 2048 B
    float* sRedA = sHid + NODES_PER_BLK * DD;                    // 8 f32
    float* sRedB = sRedA + 8;                                    // 8 f32

    int tid = threadIdx.x;

    // Stage weights once per block (amortized over 1024 nodes/block)
    for (int i = tid; i < KD * DD; i += THREADS) sW1[i] = f2bf(W1[i]);
    for (int i = tid; i < DD * DD; i += THREADS) sW2[i] = W2[i];
    __syncthreads();

    int g = tid >> 7;          // node group 0..3 within block
    int d = tid & 127;         // channel
    int w = tid >> 6;          // wave id 0..7

    float bd1 = b1[d], bd2 = b2[d], gd = gamma[d], bd = beta[d];

    for (int base = blockIdx.x * NODES_PER_BLK; base < NN; base += gridDim.x * NODES_PER_BLK) {
        int n0 = base + g;
        float* xin = sIn + g * 264;

        // ---- stage node input: [h | upstream | phys] ----
        float hval = h[(size_t)n0 * DD + d];
        xin[d] = hval;
        xin[128 + d] = up[(size_t)n0 * DD + d];
        if (d < 5) {
            float v = (d == 0) ? c1[n0] : (d == 1) ? c2[n0] : (d == 2) ? c3[n0]
                    : (d == 3) ? c4[n0] : qn[n0];
            xin[256 + d] = signed_log(v);
        }
        __syncthreads();

        // ---- GEMM1: hid[d] = silu( sum_k xin[k] * W1[k][d] + b1[d] ) ----
        float a0 = 0.f, a1 = 0.f, a2 = 0.f, a3 = 0.f;
        #pragma unroll 8
        for (int k = 0; k < 260; k += 4) {
            float4 x = *(const float4*)(xin + k);
            a0 += x.x * bf2f(sW1[(k + 0) * DD + d]);
            a1 += x.y * bf2f(sW1[(k + 1) * DD + d]);
            a2 += x.z * bf2f(sW1[(k + 2) * DD + d]);
            a3 += x.w * bf2f(sW1[(k + 3) * DD + d]);
        }
        float acc = ((a0 + a1) + (a2 + a3)) + xin[260] * bf2f(sW1[260 * DD + d]) + bd1;
        float sg = 1.f / (1.f + __expf(-acc));
        sHid[g * DD + d] = acc * sg;
        __syncthreads();

        // ---- GEMM2: z[d] = h[d] + sum_k hid[k] * W2[k][d] + b2[d] ----
        float e0 = 0.f, e1 = 0.f, e2 = 0.f, e3 = 0.f;
        const float* hin = sHid + g * DD;
        #pragma unroll 8
        for (int k = 0; k < DD; k += 4) {
            float4 x = *(const float4*)(hin + k);
            e0 += x.x * sW2[(k + 0) * DD + d];
            e1 += x.y * sW2[(k + 1) * DD + d];
            e2 += x.z * sW2[(k + 2) * DD + d];
            e3 += x.w * sW2[(k + 3) * DD + d];
        }
        float z = hval + ((e0 + e1) + (e2 + e3)) + bd2;

        // ---- LayerNorm over the 128 channels (2 waves per node) ----
        float s1 = z, s2 = z * z;
        #pragma unroll
        for (int off = 32; off >= 1; off >>= 1) {
            s1 += __shfl_xor(s1, off);
            s2 += __shfl_xor(s2, off);
        }
        if ((tid & 63) == 0) { sRedA[w] = s1; sRedB[w] = s2; }
        __syncthreads();
        float S1 = sRedA[g * 2] + sRedA[g * 2 + 1];
        float S2 = sRedB[g * 2] + sRedB[g * 2 + 1];
        float mean = S1 * (1.f / 128.f);
        float var  = S2 * (1.f / 128.f) - mean * mean;
        float rs = rsqrtf(var + 1e-5f);
        out[(size_t)n0 * DD + d] = (z - mean) * rs * gd + bd;
    }
}

extern "C" void kernel_launch(void* const* d_in, const int* in_sizes, int n_in,
                              void* d_out, int out_size, void* d_ws, size_t ws_size,
                              hipStream_t stream) {
    const float* h     = (const float*)d_in[0];
    const float* c1    = (const float*)d_in[1];
    const float* c2    = (const float*)d_in[2];
    const float* c3    = (const float*)d_in[3];
    const float* c4    = (const float*)d_in[4];
    const float* qn    = (const float*)d_in[5];
    const int*   src   = (const int*)d_in[6];
    const int*   dst   = (const int*)d_in[7];
    const float* W1    = (const float*)d_in[8];
    const float* b1    = (const float*)d_in[9];
    const float* W2    = (const float*)d_in[10];
    const float* b2    = (const float*)d_in[11];
    const float* gamma = (const float*)d_in[12];
    const float* beta  = (const float*)d_in[13];
    float* out = (float*)d_out;
    int E = in_sizes[6];

    // 1) zero the upstream accumulator (aliased with d_out)
    hipMemsetAsync(d_out, 0, (size_t)NN * DD * sizeof(float), stream);

    // 2) atomic scatter: upstream += h[src] rows
    int sthreads = E * 32;
    int sblocks = (sthreads + 255) / 256;
    scatter_kernel<<<sblocks, 256, 0, stream>>>((const float4*)h, src, dst, out, E);

    // 3) fused MLP + LN (reads upstream from d_out, overwrites with final output)
    size_t smem = (size_t)(KD * DD * 2 + DD * DD * 4
                           + NODES_PER_BLK * 264 * 4 + NODES_PER_BLK * DD * 4 + 64);
    hipFuncSetAttribute(reinterpret_cast<const void*>(node_kernel),
                        hipFuncAttributeMaxDynamicSharedMemorySize, (int)smem);
    node_kernel<<<512, THREADS, smem, stream>>>(h, out, c1, c2, c3, c4, qn,
                                                W1, b1, W2, b2, gamma, beta, out);
}

// Round 2
// 1062.646 us; speedup vs baseline: 2.6706x; 2.6706x over previous
//
#include <hip/hip_runtime.h>
#include <math.h>

#define NN 262144
#define DD 128
#define EPS_SL 1e-8f
#define EPS_LN 1e-5f
#define THREADS 512
#define TILE_M 64
#define NBLOCKS 256
#define NTILES (NN / TILE_M)          // 4096
#define TPB (NTILES / NBLOCKS)        // 16

typedef __attribute__((ext_vector_type(8))) short bf16x8;
typedef __attribute__((ext_vector_type(4))) float f32x4;

// LDS layout (bytes). All tiles in MFMA-native subtiled form [kb][row][8] bf16,
// so every A/B fragment load is one conflict-free ds_read_b128.
#define OFF_W1 0                       // [36][128][8] bf16 = 73728 B  (K=288 pad, rows 261.. zero)
#define OFF_W2 73728                   // [16][128][8] bf16 = 32768 B
#define OFF_X  106496                  // [36][64][8]  bf16 = 36864 B  (reused as LN red buffer)
#define OFF_H  143360                  // [16][64][8]  bf16 = 16384 B
#define SMEM_TOT 159744

__device__ inline unsigned short f2bf(float f) {
    union { float f; unsigned int i; } v; v.f = f;
    unsigned int r = v.i + 0x7fffu + ((v.i >> 16) & 1u);
    return (unsigned short)(r >> 16);
}
__device__ inline float signed_log(float x) {
    float l = __logf(fabsf(x) + EPS_SL);
    return (x > 0.f) ? l : ((x < 0.f) ? -l : 0.f);
}

// ---------------- scatter: upstream[dst[e]] += h[src[e]] ----------------
__global__ void scatter_kernel(const float4* __restrict__ h4,
                               const int* __restrict__ src,
                               const int* __restrict__ dst,
                               float* up, int E) {
    int tid = blockIdx.x * blockDim.x + threadIdx.x;
    int e = tid >> 5;
    if (e >= E) return;
    int c = tid & 31;
    int s = src[e];
    int d = dst[e];
    float4 v = h4[(size_t)s * 32 + c];
    float* o = up + (size_t)d * DD + c * 4;
    atomicAdd(o + 0, v.x);
    atomicAdd(o + 1, v.y);
    atomicAdd(o + 2, v.z);
    atomicAdd(o + 3, v.w);
}

// ---------------- fused MFMA node MLP + LayerNorm ----------------
// up aliases out: each block reads upstream rows of its own tile before
// overwriting them with the final output (same-block ordering, race-free).
__global__ __launch_bounds__(THREADS) void node_kernel(
    const float* __restrict__ h, const float* up,
    const float* __restrict__ c1, const float* __restrict__ c2,
    const float* __restrict__ c3, const float* __restrict__ c4,
    const float* __restrict__ qn,
    const float* __restrict__ W1, const float* __restrict__ b1,
    const float* __restrict__ W2, const float* __restrict__ b2,
    const float* __restrict__ gamma, const float* __restrict__ beta,
    float* out)
{
    extern __shared__ char smem[];
    unsigned short* sW1 = (unsigned short*)(smem + OFF_W1);
    unsigned short* sW2 = (unsigned short*)(smem + OFF_W2);
    unsigned short* sX  = (unsigned short*)(smem + OFF_X);
    unsigned short* sH  = (unsigned short*)(smem + OFF_H);
    float2* red = (float2*)(smem + OFF_X);   // [4 wn][64 rows], X is dead by then

    const int tid = threadIdx.x;

    // ---- stage transposed bf16 weights once per block ----
    // W1t[kb][n][j] = W1[kb*8+j][n] (0 beyond k=260). Coalesced global reads.
    for (int c = tid; c < 36 * 128; c += THREADS) {
        int kb = c >> 7, n = c & 127;
        unsigned short tmp[8] __attribute__((aligned(16)));
        #pragma unroll
        for (int j = 0; j < 8; ++j) {
            int k = kb * 8 + j;
            tmp[j] = (k < 261) ? f2bf(W1[k * DD + n]) : (unsigned short)0;
        }
        *(uint4*)(sW1 + c * 8) = *(const uint4*)tmp;
    }
    for (int c = tid; c < 16 * 128; c += THREADS) {
        int kb = c >> 7, n = c & 127;
        unsigned short tmp[8] __attribute__((aligned(16)));
        #pragma unroll
        for (int j = 0; j < 8; ++j) tmp[j] = f2bf(W2[(kb * 8 + j) * DD + n]);
        *(uint4*)(sW2 + c * 8) = *(const uint4*)tmp;
    }
    __syncthreads();

    const int lane = tid & 63;
    const int w    = tid >> 6;     // 0..7
    const int wm   = w >> 2;       // 0..1  (32-row half)
    const int wn   = w & 3;        // 0..3  (32-col quarter)
    const int l15  = lane & 15;
    const int lk   = lane >> 4;    // 0..3
    const int col0 = wn * 32 + l15;
    const int col1 = col0 + 16;

    const float b1v[2] = {b1[col0], b1[col1]};
    const float b2v[2] = {b2[col0], b2[col1]};
    const float gv[2]  = {gamma[col0], gamma[col1]};
    const float bv[2]  = {beta[col0], beta[col1]};

    const bf16x8* Xf  = (const bf16x8*)sX;
    const bf16x8* W1f = (const bf16x8*)sW1;
    const bf16x8* Hf  = (const bf16x8*)sH;
    const bf16x8* W2f = (const bf16x8*)sW2;

    for (int t = blockIdx.x * TPB; t < blockIdx.x * TPB + TPB; ++t) {
        const int base = t * TILE_M;
        __syncthreads();   // sX/red reuse from previous iteration

        // ---- stage X tile: [h | upstream | phys | 0-pad] as bf16 ----
        #pragma unroll
        for (int i = 0; i < 4; ++i) {
            int chunk = i * THREADS + tid;      // kb*64 + row, kb 0..31
            int kb = chunk >> 6, row = chunk & 63;
            const float* src = (kb < 16) ? (h  + (size_t)(base + row) * DD + kb * 8)
                                         : (up + (size_t)(base + row) * DD + (kb - 16) * 8);
            float4 p0 = *(const float4*)src;
            float4 p1 = *(const float4*)(src + 4);
            unsigned short tmp[8] __attribute__((aligned(16)));
            tmp[0] = f2bf(p0.x); tmp[1] = f2bf(p0.y); tmp[2] = f2bf(p0.z); tmp[3] = f2bf(p0.w);
            tmp[4] = f2bf(p1.x); tmp[5] = f2bf(p1.y); tmp[6] = f2bf(p1.z); tmp[7] = f2bf(p1.w);
            *(uint4*)(sX + chunk * 8) = *(const uint4*)tmp;
        }
        if (tid < 256) {                        // kb 32..35: phys + zero pad
            int kb = 32 + (tid >> 6), row = tid & 63;
            unsigned short tmp[8] __attribute__((aligned(16))) = {0,0,0,0,0,0,0,0};
            if (kb == 32) {
                int n0 = base + row;
                tmp[0] = f2bf(signed_log(c1[n0]));
                tmp[1] = f2bf(signed_log(c2[n0]));
                tmp[2] = f2bf(signed_log(c3[n0]));
                tmp[3] = f2bf(signed_log(c4[n0]));
                tmp[4] = f2bf(signed_log(qn[n0]));
            }
            *(uint4*)(sX + (kb * 64 + row) * 8) = *(const uint4*)tmp;
        }
        __syncthreads();

        // ---- GEMM1: (64x288) @ (288x128), K-step 32 ----
        f32x4 acc[2][2] = {};
        #pragma unroll
        for (int ks = 0; ks < 9; ++ks) {
            int kb = ks * 4 + lk;
            bf16x8 a0  = Xf[kb * 64 + wm * 32 + l15];
            bf16x8 a1  = Xf[kb * 64 + wm * 32 + 16 + l15];
            bf16x8 bb0 = W1f[kb * 128 + col0];
            bf16x8 bb1 = W1f[kb * 128 + col1];
            acc[0][0] = __builtin_amdgcn_mfma_f32_16x16x32_bf16(a0, bb0, acc[0][0], 0, 0, 0);
            acc[0][1] = __builtin_amdgcn_mfma_f32_16x16x32_bf16(a0, bb1, acc[0][1], 0, 0, 0);
            acc[1][0] = __builtin_amdgcn_mfma_f32_16x16x32_bf16(a1, bb0, acc[1][0], 0, 0, 0);
            acc[1][1] = __builtin_amdgcn_mfma_f32_16x16x32_bf16(a1, bb1, acc[1][1], 0, 0, 0);
        }
        // silu -> hid tile (bf16, subtiled layout)
        #pragma unroll
        for (int fm = 0; fm < 2; ++fm) {
            int row = wm * 32 + fm * 16 + lk * 4;
            #pragma unroll
            for (int fn = 0; fn < 2; ++fn) {
                int col = wn * 32 + fn * 16 + l15;
                int kbh = col >> 3, ko = col & 7;
                #pragma unroll
                for (int r = 0; r < 4; ++r) {
                    float v = acc[fm][fn][r] + b1v[fn];
                    float sg = 1.f / (1.f + __expf(-v));
                    sH[(kbh * 64 + row + r) * 8 + ko] = f2bf(v * sg);
                }
            }
        }
        __syncthreads();

        // ---- GEMM2: (64x128) @ (128x128) ----
        f32x4 acc2[2][2] = {};
        #pragma unroll
        for (int ks = 0; ks < 4; ++ks) {
            int kb = ks * 4 + lk;
            bf16x8 a0  = Hf[kb * 64 + wm * 32 + l15];
            bf16x8 a1  = Hf[kb * 64 + wm * 32 + 16 + l15];
            bf16x8 bb0 = W2f[kb * 128 + col0];
            bf16x8 bb1 = W2f[kb * 128 + col1];
            acc2[0][0] = __builtin_amdgcn_mfma_f32_16x16x32_bf16(a0, bb0, acc2[0][0], 0, 0, 0);
            acc2[0][1] = __builtin_amdgcn_mfma_f32_16x16x32_bf16(a0, bb1, acc2[0][1], 0, 0, 0);
            acc2[1][0] = __builtin_amdgcn_mfma_f32_16x16x32_bf16(a1, bb0, acc2[1][0], 0, 0, 0);
            acc2[1][1] = __builtin_amdgcn_mfma_f32_16x16x32_bf16(a1, bb1, acc2[1][1], 0, 0, 0);
        }

        // ---- residual + LN partial sums (over this wave's 32 cols) ----
        float rs1[2][4], rs2[2][4];
        #pragma unroll
        for (int fm = 0; fm < 2; ++fm) {
            #pragma unroll
            for (int r = 0; r < 4; ++r) {
                size_t rowg = (size_t)(base + wm * 32 + fm * 16 + lk * 4 + r) * DD;
                float z0 = acc2[fm][0][r] + b2v[0] + h[rowg + col0];
                float z1 = acc2[fm][1][r] + b2v[1] + h[rowg + col1];
                acc2[fm][0][r] = z0; acc2[fm][1][r] = z1;
                float s = z0 + z1, q = z0 * z0 + z1 * z1;
                #pragma unroll
                for (int off = 1; off < 16; off <<= 1) {
                    s += __shfl_xor(s, off);
                    q += __shfl_xor(q, off);
                }
                rs1[fm][r] = s; rs2[fm][r] = q;
            }
        }
        if (l15 == 0) {
            #pragma unroll
            for (int fm = 0; fm < 2; ++fm)
                #pragma unroll
                for (int r = 0; r < 4; ++r)
                    red[wn * 64 + wm * 32 + fm * 16 + lk * 4 + r] =
                        make_float2(rs1[fm][r], rs2[fm][r]);
        }
        __syncthreads();

        // ---- combine partials, normalize, store ----
        #pragma unroll
        for (int fm = 0; fm < 2; ++fm) {
            #pragma unroll
            for (int r = 0; r < 4; ++r) {
                int rloc = wm * 32 + fm * 16 + lk * 4 + r;
                float2 t0 = red[rloc], t1 = red[64 + rloc],
                       t2 = red[128 + rloc], t3 = red[192 + rloc];
                float S = t0.x + t1.x + t2.x + t3.x;
                float Q = t0.y + t1.y + t2.y + t3.y;
                float mean = S * (1.f / 128.f);
                float var  = Q * (1.f / 128.f) - mean * mean;
                float rstd = rsqrtf(var + EPS_LN);
                size_t rowg = (size_t)(base + rloc) * DD;
                out[rowg + col0] = (acc2[fm][0][r] - mean) * rstd * gv[0] + bv[0];
                out[rowg + col1] = (acc2[fm][1][r] - mean) * rstd * gv[1] + bv[1];
            }
        }
    }
}

extern "C" void kernel_launch(void* const* d_in, const int* in_sizes, int n_in,
                              void* d_out, int out_size, void* d_ws, size_t ws_size,
                              hipStream_t stream) {
    const float* h     = (const float*)d_in[0];
    const float* c1    = (const float*)d_in[1];
    const float* c2    = (const float*)d_in[2];
    const float* c3    = (const float*)d_in[3];
    const float* c4    = (const float*)d_in[4];
    const float* qn    = (const float*)d_in[5];
    const int*   src   = (const int*)d_in[6];
    const int*   dst   = (const int*)d_in[7];
    const float* W1    = (const float*)d_in[8];
    const float* b1    = (const float*)d_in[9];
    const float* W2    = (const float*)d_in[10];
    const float* b2    = (const float*)d_in[11];
    const float* gamma = (const float*)d_in[12];
    const float* beta  = (const float*)d_in[13];
    float* out = (float*)d_out;
    int E = in_sizes[6];

    // 1) zero upstream accumulator (aliased with d_out)
    hipMemsetAsync(d_out, 0, (size_t)NN * DD * sizeof(float), stream);

    // 2) atomic scatter
    int sthreads = E * 32;
    int sblocks = (sthreads + 255) / 256;
    scatter_kernel<<<sblocks, 256, 0, stream>>>((const float4*)h, src, dst, out, E);

    // 3) fused MFMA MLP + LN
    hipFuncSetAttribute(reinterpret_cast<const void*>(node_kernel),
                        hipFuncAttributeMaxDynamicSharedMemorySize, SMEM_TOT);
    node_kernel<<<NBLOCKS, THREADS, SMEM_TOT, stream>>>(h, out, c1, c2, c3, c4, qn,
                                                        W1, b1, W2, b2, gamma, beta, out);
}

// Round 3
// 296.352 us; speedup vs baseline: 9.5762x; 3.5858x over previous
//
#include <hip/hip_runtime.h>
#include <math.h>

#define NN 262144
#define DD 128
#define EPS_SL 1e-8f
#define EPS_LN 1e-5f
#define THREADS 512
#define TILE_M 64
#define NBLOCKS 256
#define NTILES (NN / TILE_M)          // 4096
#define TPB (NTILES / NBLOCKS)        // 16

typedef __attribute__((ext_vector_type(8))) short bf16x8;
typedef __attribute__((ext_vector_type(4))) float f32x4;

// LDS layout (bytes). All tiles in MFMA-native subtiled form [kb][row][8] bf16,
// so every A/B fragment load is one conflict-free ds_read_b128.
#define OFF_W1 0                       // [36][128][8] bf16 = 73728 B  (K=288 pad)
#define OFF_W2 73728                   // [16][128][8] bf16 = 32768 B
#define OFF_X  106496                  // [36][64][8]  bf16 = 36864 B  (reused as LN red)
#define OFF_H  143360                  // [16][64][8]  bf16 = 16384 B
#define SMEM_TOT 159744

// d_ws layout (CSR build)
#define WS_OFFS   0                    // (NN+1) int
#define WS_CURSOR 1048832              // NN int
#define WS_BSUM   2097408              // 1024 int
#define WS_ESRC   2101504              // E int
#define WS_NEEDED (2101504 + 524288 * 4)

__device__ inline unsigned short f2bf(float f) {
    union { float f; unsigned int i; } v; v.f = f;
    unsigned int r = v.i + 0x7fffu + ((v.i >> 16) & 1u);
    return (unsigned short)(r >> 16);
}
__device__ inline float signed_log(float x) {
    float l = __logf(fabsf(x) + EPS_SL);
    return (x > 0.f) ? l : ((x < 0.f) ? -l : 0.f);
}

// ---------------- CSR build ----------------
__global__ void hist_kernel(const int* __restrict__ dst, int* counts, int E) {
    int e = blockIdx.x * blockDim.x + threadIdx.x;
    if (e < E) atomicAdd(&counts[dst[e]], 1);
}

// per-256-block exclusive scan (in place), block totals to bsum
__global__ void scan_local(int* offs, int* bsum) {
    __shared__ int tmp[256];
    int t = threadIdx.x, i = blockIdx.x * 256 + t;
    int own = offs[i];
    tmp[t] = own;
    __syncthreads();
    for (int off = 1; off < 256; off <<= 1) {
        int v = (t >= off) ? tmp[t - off] : 0;
        __syncthreads();
        tmp[t] += v;
        __syncthreads();
    }
    offs[i] = tmp[t] - own;
    if (t == 255) bsum[blockIdx.x] = tmp[255];
}

__global__ void scan_bsum(int* bsum) {
    __shared__ int tmp[1024];
    int t = threadIdx.x;
    int own = bsum[t];
    tmp[t] = own;
    __syncthreads();
    for (int off = 1; off < 1024; off <<= 1) {
        int v = (t >= off) ? tmp[t - off] : 0;
        __syncthreads();
        tmp[t] += v;
        __syncthreads();
    }
    bsum[t] = tmp[t] - own;
}

__global__ void scan_fixup(int* offs, const int* __restrict__ bsum, int* cursor, int E) {
    int i = blockIdx.x * 256 + threadIdx.x;
    int v = offs[i] + bsum[i >> 8];
    offs[i] = v;
    cursor[i] = v;
    if (i == 0) offs[NN] = E;
}

__global__ void fill_kernel(const int* __restrict__ src, const int* __restrict__ dst,
                            int* cursor, int* esrc, int E) {
    int e = blockIdx.x * blockDim.x + threadIdx.x;
    if (e < E) {
        int p = atomicAdd(&cursor[dst[e]], 1);
        esrc[p] = src[e];
    }
}

// ---------------- fallback atomic scatter ----------------
__global__ void scatter_kernel(const float4* __restrict__ h4,
                               const int* __restrict__ src,
                               const int* __restrict__ dst,
                               float* up, int E) {
    int tid = blockIdx.x * blockDim.x + threadIdx.x;
    int e = tid >> 5;
    if (e >= E) return;
    int c = tid & 31;
    float4 v = h4[(size_t)src[e] * 32 + c];
    float* o = up + (size_t)dst[e] * DD + c * 4;
    atomicAdd(o + 0, v.x);
    atomicAdd(o + 1, v.y);
    atomicAdd(o + 2, v.z);
    atomicAdd(o + 3, v.w);
}

// ---------------- fused gather + MFMA MLP + LayerNorm ----------------
template <int GATHER>
__global__ __launch_bounds__(THREADS) void node_kernel(
    const float* __restrict__ h, const float* up,
    const int* __restrict__ offs, const int* __restrict__ esrc,
    const float* __restrict__ c1, const float* __restrict__ c2,
    const float* __restrict__ c3, const float* __restrict__ c4,
    const float* __restrict__ qn,
    const float* __restrict__ W1, const float* __restrict__ b1,
    const float* __restrict__ W2, const float* __restrict__ b2,
    const float* __restrict__ gamma, const float* __restrict__ beta,
    float* out)
{
    extern __shared__ char smem[];
    unsigned short* sW1 = (unsigned short*)(smem + OFF_W1);
    unsigned short* sW2 = (unsigned short*)(smem + OFF_W2);
    unsigned short* sX  = (unsigned short*)(smem + OFF_X);
    unsigned short* sH  = (unsigned short*)(smem + OFF_H);
    float2* red = (float2*)(smem + OFF_X);   // X dead by LN-reduce time

    const int tid = threadIdx.x;

    // ---- stage transposed bf16 weights once per block ----
    for (int c = tid; c < 36 * 128; c += THREADS) {
        int kb = c >> 7, n = c & 127;
        unsigned short tmp[8] __attribute__((aligned(16)));
        #pragma unroll
        for (int j = 0; j < 8; ++j) {
            int k = kb * 8 + j;
            tmp[j] = (k < 261) ? f2bf(W1[k * DD + n]) : (unsigned short)0;
        }
        *(uint4*)(sW1 + c * 8) = *(const uint4*)tmp;
    }
    for (int c = tid; c < 16 * 128; c += THREADS) {
        int kb = c >> 7, n = c & 127;
        unsigned short tmp[8] __attribute__((aligned(16)));
        #pragma unroll
        for (int j = 0; j < 8; ++j) tmp[j] = f2bf(W2[(kb * 8 + j) * DD + n]);
        *(uint4*)(sW2 + c * 8) = *(const uint4*)tmp;
    }
    __syncthreads();

    const int lane = tid & 63;
    const int w    = tid >> 6;
    const int wm   = w >> 2;
    const int wn   = w & 3;
    const int l15  = lane & 15;
    const int lk   = lane >> 4;
    const int col0 = wn * 32 + l15;
    const int col1 = col0 + 16;

    const float b1v[2] = {b1[col0], b1[col1]};
    const float b2v[2] = {b2[col0], b2[col1]};
    const float gv[2]  = {gamma[col0], gamma[col1]};
    const float bv[2]  = {beta[col0], beta[col1]};

    const bf16x8* Xf  = (const bf16x8*)sX;
    const bf16x8* W1f = (const bf16x8*)sW1;
    const bf16x8* Hf  = (const bf16x8*)sH;
    const bf16x8* W2f = (const bf16x8*)sW2;

    for (int t = blockIdx.x * TPB; t < blockIdx.x * TPB + TPB; ++t) {
        const int base = t * TILE_M;
        __syncthreads();   // sX/red reuse from previous iteration

        // ---- stage X tile: h rows (kb 0..15) ----
        #pragma unroll
        for (int i = 0; i < 2; ++i) {
            int chunk = i * THREADS + tid;      // kb*64 + row, kb 0..15
            int kb = chunk >> 6, row = chunk & 63;
            const float* srcp = h + (size_t)(base + row) * DD + kb * 8;
            float4 p0 = *(const float4*)srcp;
            float4 p1 = *(const float4*)(srcp + 4);
            unsigned short tmp[8] __attribute__((aligned(16)));
            tmp[0] = f2bf(p0.x); tmp[1] = f2bf(p0.y); tmp[2] = f2bf(p0.z); tmp[3] = f2bf(p0.w);
            tmp[4] = f2bf(p1.x); tmp[5] = f2bf(p1.y); tmp[6] = f2bf(p1.z); tmp[7] = f2bf(p1.w);
            *(uint4*)(sX + chunk * 8) = *(const uint4*)tmp;
        }

        // ---- upstream (kb 16..31) ----
        if (GATHER) {
            // 8 threads per node; each handles 2 kb-entries of 8 floats.
            int nl = tid >> 3;                  // 0..63 local node
            int n0 = base + nl;
            int o0 = offs[n0], o1 = offs[n0 + 1];
            #pragma unroll
            for (int half = 0; half < 2; ++half) {
                int kbu = (tid & 7) + half * 8; // 0..15
                float4 a = make_float4(0.f, 0.f, 0.f, 0.f);
                float4 b = make_float4(0.f, 0.f, 0.f, 0.f);
                for (int e = o0; e < o1; ++e) {
                    const float* hr = h + (size_t)esrc[e] * DD + kbu * 8;
                    float4 p0 = *(const float4*)hr;
                    float4 p1 = *(const float4*)(hr + 4);
                    a.x += p0.x; a.y += p0.y; a.z += p0.z; a.w += p0.w;
                    b.x += p1.x; b.y += p1.y; b.z += p1.z; b.w += p1.w;
                }
                unsigned short tmp[8] __attribute__((aligned(16)));
                tmp[0] = f2bf(a.x); tmp[1] = f2bf(a.y); tmp[2] = f2bf(a.z); tmp[3] = f2bf(a.w);
                tmp[4] = f2bf(b.x); tmp[5] = f2bf(b.y); tmp[6] = f2bf(b.z); tmp[7] = f2bf(b.w);
                *(uint4*)(sX + ((16 + kbu) * 64 + nl) * 8) = *(const uint4*)tmp;
            }
        } else {
            #pragma unroll
            for (int i = 0; i < 2; ++i) {
                int chunk = i * THREADS + tid;
                int kb = chunk >> 6, row = chunk & 63;
                const float* srcp = up + (size_t)(base + row) * DD + kb * 8;
                float4 p0 = *(const float4*)srcp;
                float4 p1 = *(const float4*)(srcp + 4);
                unsigned short tmp[8] __attribute__((aligned(16)));
                tmp[0] = f2bf(p0.x); tmp[1] = f2bf(p0.y); tmp[2] = f2bf(p0.z); tmp[3] = f2bf(p0.w);
                tmp[4] = f2bf(p1.x); tmp[5] = f2bf(p1.y); tmp[6] = f2bf(p1.z); tmp[7] = f2bf(p1.w);
                *(uint4*)(sX + ((16 + kb) * 64 + row) * 8) = *(const uint4*)tmp;
            }
        }

        // ---- phys (kb 32..35) ----
        if (tid < 256) {
            int kb = 32 + (tid >> 6), row = tid & 63;
            unsigned short tmp[8] __attribute__((aligned(16))) = {0,0,0,0,0,0,0,0};
            if (kb == 32) {
                int n0 = base + row;
                tmp[0] = f2bf(signed_log(c1[n0]));
                tmp[1] = f2bf(signed_log(c2[n0]));
                tmp[2] = f2bf(signed_log(c3[n0]));
                tmp[3] = f2bf(signed_log(c4[n0]));
                tmp[4] = f2bf(signed_log(qn[n0]));
            }
            *(uint4*)(sX + (kb * 64 + row) * 8) = *(const uint4*)tmp;
        }
        __syncthreads();

        // ---- GEMM1: (64x288) @ (288x128) ----
        f32x4 acc[2][2] = {};
        #pragma unroll
        for (int ks = 0; ks < 9; ++ks) {
            int kb = ks * 4 + lk;
            bf16x8 a0  = Xf[kb * 64 + wm * 32 + l15];
            bf16x8 a1  = Xf[kb * 64 + wm * 32 + 16 + l15];
            bf16x8 bb0 = W1f[kb * 128 + col0];
            bf16x8 bb1 = W1f[kb * 128 + col1];
            acc[0][0] = __builtin_amdgcn_mfma_f32_16x16x32_bf16(a0, bb0, acc[0][0], 0, 0, 0);
            acc[0][1] = __builtin_amdgcn_mfma_f32_16x16x32_bf16(a0, bb1, acc[0][1], 0, 0, 0);
            acc[1][0] = __builtin_amdgcn_mfma_f32_16x16x32_bf16(a1, bb0, acc[1][0], 0, 0, 0);
            acc[1][1] = __builtin_amdgcn_mfma_f32_16x16x32_bf16(a1, bb1, acc[1][1], 0, 0, 0);
        }
        #pragma unroll
        for (int fm = 0; fm < 2; ++fm) {
            int row = wm * 32 + fm * 16 + lk * 4;
            #pragma unroll
            for (int fn = 0; fn < 2; ++fn) {
                int col = wn * 32 + fn * 16 + l15;
                int kbh = col >> 3, ko = col & 7;
                #pragma unroll
                for (int r = 0; r < 4; ++r) {
                    float v = acc[fm][fn][r] + b1v[fn];
                    float sg = 1.f / (1.f + __expf(-v));
                    sH[(kbh * 64 + row + r) * 8 + ko] = f2bf(v * sg);
                }
            }
        }
        __syncthreads();

        // ---- GEMM2: (64x128) @ (128x128) ----
        f32x4 acc2[2][2] = {};
        #pragma unroll
        for (int ks = 0; ks < 4; ++ks) {
            int kb = ks * 4 + lk;
            bf16x8 a0  = Hf[kb * 64 + wm * 32 + l15];
            bf16x8 a1  = Hf[kb * 64 + wm * 32 + 16 + l15];
            bf16x8 bb0 = W2f[kb * 128 + col0];
            bf16x8 bb1 = W2f[kb * 128 + col1];
            acc2[0][0] = __builtin_amdgcn_mfma_f32_16x16x32_bf16(a0, bb0, acc2[0][0], 0, 0, 0);
            acc2[0][1] = __builtin_amdgcn_mfma_f32_16x16x32_bf16(a0, bb1, acc2[0][1], 0, 0, 0);
            acc2[1][0] = __builtin_amdgcn_mfma_f32_16x16x32_bf16(a1, bb0, acc2[1][0], 0, 0, 0);
            acc2[1][1] = __builtin_amdgcn_mfma_f32_16x16x32_bf16(a1, bb1, acc2[1][1], 0, 0, 0);
        }

        // ---- residual + LN partials ----
        float rs1[2][4], rs2[2][4];
        #pragma unroll
        for (int fm = 0; fm < 2; ++fm) {
            #pragma unroll
            for (int r = 0; r < 4; ++r) {
                size_t rowg = (size_t)(base + wm * 32 + fm * 16 + lk * 4 + r) * DD;
                float z0 = acc2[fm][0][r] + b2v[0] + h[rowg + col0];
                float z1 = acc2[fm][1][r] + b2v[1] + h[rowg + col1];
                acc2[fm][0][r] = z0; acc2[fm][1][r] = z1;
                float s = z0 + z1, q = z0 * z0 + z1 * z1;
                #pragma unroll
                for (int off = 1; off < 16; off <<= 1) {
                    s += __shfl_xor(s, off);
                    q += __shfl_xor(q, off);
                }
                rs1[fm][r] = s; rs2[fm][r] = q;
            }
        }
        if (l15 == 0) {
            #pragma unroll
            for (int fm = 0; fm < 2; ++fm)
                #pragma unroll
                for (int r = 0; r < 4; ++r)
                    red[wn * 64 + wm * 32 + fm * 16 + lk * 4 + r] =
                        make_float2(rs1[fm][r], rs2[fm][r]);
        }
        __syncthreads();

        #pragma unroll
        for (int fm = 0; fm < 2; ++fm) {
            #pragma unroll
            for (int r = 0; r < 4; ++r) {
                int rloc = wm * 32 + fm * 16 + lk * 4 + r;
                float2 t0 = red[rloc], t1 = red[64 + rloc],
                       t2 = red[128 + rloc], t3 = red[192 + rloc];
                float S = t0.x + t1.x + t2.x + t3.x;
                float Q = t0.y + t1.y + t2.y + t3.y;
                float mean = S * (1.f / 128.f);
                float var  = Q * (1.f / 128.f) - mean * mean;
                float rstd = rsqrtf(var + EPS_LN);
                size_t rowg = (size_t)(base + rloc) * DD;
                out[rowg + col0] = (acc2[fm][0][r] - mean) * rstd * gv[0] + bv[0];
                out[rowg + col1] = (acc2[fm][1][r] - mean) * rstd * gv[1] + bv[1];
            }
        }
    }
}

extern "C" void kernel_launch(void* const* d_in, const int* in_sizes, int n_in,
                              void* d_out, int out_size, void* d_ws, size_t ws_size,
                              hipStream_t stream) {
    const float* h     = (const float*)d_in[0];
    const float* c1    = (const float*)d_in[1];
    const float* c2    = (const float*)d_in[2];
    const float* c3    = (const float*)d_in[3];
    const float* c4    = (const float*)d_in[4];
    const float* qn    = (const float*)d_in[5];
    const int*   src   = (const int*)d_in[6];
    const int*   dst   = (const int*)d_in[7];
    const float* W1    = (const float*)d_in[8];
    const float* b1    = (const float*)d_in[9];
    const float* W2    = (const float*)d_in[10];
    const float* b2    = (const float*)d_in[11];
    const float* gamma = (const float*)d_in[12];
    const float* beta  = (const float*)d_in[13];
    float* out = (float*)d_out;
    int E = in_sizes[6];

    if (ws_size >= (size_t)WS_NEEDED) {
        char* ws = (char*)d_ws;
        int* offs   = (int*)(ws + WS_OFFS);
        int* cursor = (int*)(ws + WS_CURSOR);
        int* bsum   = (int*)(ws + WS_BSUM);
        int* esrc   = (int*)(ws + WS_ESRC);

        hipMemsetAsync(offs, 0, (size_t)NN * sizeof(int), stream);
        int eb = (E + 255) / 256;
        hist_kernel<<<eb, 256, 0, stream>>>(dst, offs, E);
        scan_local<<<NN / 256, 256, 0, stream>>>(offs, bsum);
        scan_bsum<<<1, 1024, 0, stream>>>(bsum);
        scan_fixup<<<NN / 256, 256, 0, stream>>>(offs, bsum, cursor, E);
        fill_kernel<<<eb, 256, 0, stream>>>(src, dst, cursor, esrc, E);

        hipFuncSetAttribute(reinterpret_cast<const void*>(&node_kernel<1>),
                            hipFuncAttributeMaxDynamicSharedMemorySize, SMEM_TOT);
        node_kernel<1><<<NBLOCKS, THREADS, SMEM_TOT, stream>>>(
            h, nullptr, offs, esrc, c1, c2, c3, c4, qn,
            W1, b1, W2, b2, gamma, beta, out);
    } else {
        // fallback: atomic scatter into d_out (aliased as upstream)
        hipMemsetAsync(d_out, 0, (size_t)NN * DD * sizeof(float), stream);
        int sthreads = E * 32;
        int sblocks = (sthreads + 255) / 256;
        scatter_kernel<<<sblocks, 256, 0, stream>>>((const float4*)h, src, dst, out, E);
        hipFuncSetAttribute(reinterpret_cast<const void*>(&node_kernel<0>),
                            hipFuncAttributeMaxDynamicSharedMemorySize, SMEM_TOT);
        node_kernel<0><<<NBLOCKS, THREADS, SMEM_TOT, stream>>>(
            h, out, nullptr, nullptr, c1, c2, c3, c4, qn,
            W1, b1, W2, b2, gamma, beta, out);
    }
}

// Round 4
// 232.567 us; speedup vs baseline: 12.2027x; 1.2743x over previous
//
#include <hip/hip_runtime.h>
#include <math.h>

#define NN 262144
#define DD 128
#define EPS_SL 1e-8f
#define EPS_LN 1e-5f
#define THREADS 512
#define TILE_M 64
#define NBLOCKS 256
#define NTILES (NN / TILE_M)          // 4096
#define TPB (NTILES / NBLOCKS)        // 16

typedef __attribute__((ext_vector_type(8))) short bf16x8;
typedef __attribute__((ext_vector_type(4))) float f32x4;

// LDS layout (bytes). Subtiled MFMA-native [kb][row][8] bf16; X is XOR-swizzled
// (unit index ^= kb&7) so both the coalesced-stage writes and A-fragment reads
// are bank-conflict-light.
#define OFF_W1 0                       // [36][128][8] bf16 = 73728 B  (K=288 pad)
#define OFF_W2 73728                   // [16][128][8] bf16 = 32768 B
#define OFF_X  106496                  // [36][64][8]  bf16 = 36864 B
#define OFF_H  143360                  // [16][64][8]  bf16 = 16384 B
#define OFF_RED 159744                 // 256 float2   =  2048 B
#define SMEM_TOT 161792

// d_ws layout (CSR build)
#define WS_OFFS   0                    // (NN+1) int
#define WS_CURSOR 1048832              // NN int
#define WS_BSUM   2097408              // 1024 int
#define WS_ESRC   2101504              // E int
#define WS_NEEDED (2101504 + 524288 * 4)

__device__ inline unsigned short f2bf(float f) {
    union { float f; unsigned int i; } v; v.f = f;
    unsigned int r = v.i + 0x7fffu + ((v.i >> 16) & 1u);
    return (unsigned short)(r >> 16);
}
__device__ inline unsigned int pack2(float a, float b) {
    return (unsigned int)f2bf(a) | ((unsigned int)f2bf(b) << 16);
}
__device__ inline uint4 pack8(float4 a, float4 b) {
    return make_uint4(pack2(a.x, a.y), pack2(a.z, a.w),
                      pack2(b.x, b.y), pack2(b.z, b.w));
}
__device__ inline float signed_log(float x) {
    float l = __logf(fabsf(x) + EPS_SL);
    return (x > 0.f) ? l : ((x < 0.f) ? -l : 0.f);
}
// swizzled X store/load: unit index (kb*64+row) ^ (kb&7)
__device__ inline void stx(unsigned short* sX, int kb, int row, uint4 v) {
    *(uint4*)(sX + (((kb * 64 + row) ^ (kb & 7)) * 8)) = v;
}
__device__ inline bf16x8 ldx(const unsigned short* sX, int kb, int row) {
    return *(const bf16x8*)(sX + (((kb * 64 + row) ^ (kb & 7)) * 8));
}

// ---------------- CSR build ----------------
__global__ void hist_kernel(const int* __restrict__ dst, int* counts, int E) {
    int e = blockIdx.x * blockDim.x + threadIdx.x;
    if (e < E) atomicAdd(&counts[dst[e]], 1);
}

__global__ void scan_local(int* offs, int* bsum) {
    __shared__ int tmp[256];
    int t = threadIdx.x, i = blockIdx.x * 256 + t;
    int own = offs[i];
    tmp[t] = own;
    __syncthreads();
    for (int off = 1; off < 256; off <<= 1) {
        int v = (t >= off) ? tmp[t - off] : 0;
        __syncthreads();
        tmp[t] += v;
        __syncthreads();
    }
    offs[i] = tmp[t] - own;
    if (t == 255) bsum[blockIdx.x] = tmp[255];
}

__global__ void scan_bsum(int* bsum) {
    __shared__ int tmp[1024];
    int t = threadIdx.x;
    int own = bsum[t];
    tmp[t] = own;
    __syncthreads();
    for (int off = 1; off < 1024; off <<= 1) {
        int v = (t >= off) ? tmp[t - off] : 0;
        __syncthreads();
        tmp[t] += v;
        __syncthreads();
    }
    bsum[t] = tmp[t] - own;
}

__global__ void scan_fixup(int* offs, const int* __restrict__ bsum, int* cursor, int E) {
    int i = blockIdx.x * 256 + threadIdx.x;
    int v = offs[i] + bsum[i >> 8];
    offs[i] = v;
    cursor[i] = v;
    if (i == 0) offs[NN] = E;
}

__global__ void fill_kernel(const int* __restrict__ src, const int* __restrict__ dst,
                            int* cursor, int* esrc, int E) {
    int e = blockIdx.x * blockDim.x + threadIdx.x;
    if (e < E) {
        int p = atomicAdd(&cursor[dst[e]], 1);
        esrc[p] = src[e];
    }
}

// ---------------- CSR gather -> upstream bf16 (one row per 512B out slot) ----
__global__ __launch_bounds__(256) void gather_kernel(
    const float4* __restrict__ h4, const int* __restrict__ offs,
    const int* __restrict__ esrc, char* outb)
{
    int stride = gridDim.x * 256;
    for (int idx = blockIdx.x * 256 + threadIdx.x; idx < NN * 16; idx += stride) {
        int n = idx >> 4, c = idx & 15;
        int o0 = offs[n], o1 = offs[n + 1];
        float4 a = make_float4(0.f, 0.f, 0.f, 0.f);
        float4 b = make_float4(0.f, 0.f, 0.f, 0.f);
        for (int e = o0; e < o1; ++e) {
            const float4* hr = h4 + (size_t)esrc[e] * 32 + c * 2;
            float4 p0 = hr[0], p1 = hr[1];
            a.x += p0.x; a.y += p0.y; a.z += p0.z; a.w += p0.w;
            b.x += p1.x; b.y += p1.y; b.z += p1.z; b.w += p1.w;
        }
        *(uint4*)(outb + (size_t)n * 512 + c * 16) = pack8(a, b);
    }
}

// ---------------- fallback atomic scatter ----------------
__global__ void scatter_kernel(const float4* __restrict__ h4,
                               const int* __restrict__ src,
                               const int* __restrict__ dst,
                               float* up, int E) {
    int tid = blockIdx.x * blockDim.x + threadIdx.x;
    int e = tid >> 5;
    if (e >= E) return;
    int c = tid & 31;
    float4 v = h4[(size_t)src[e] * 32 + c];
    float* o = up + (size_t)dst[e] * DD + c * 4;
    atomicAdd(o + 0, v.x);
    atomicAdd(o + 1, v.y);
    atomicAdd(o + 2, v.z);
    atomicAdd(o + 3, v.w);
}

// ---------------- pipelined MFMA node MLP + LayerNorm ----------------
// GATHER=1: up = bf16 rows at (char*)out + n*512 (written by gather_kernel)
// GATHER=0: up = fp32 rows in out (written by scatter_kernel)
// Aliasing safe: block reads only its own tiles' rows; writes them afterwards.
template <int GATHER>
__global__ __launch_bounds__(THREADS) void node_kernel(
    const float* __restrict__ h, const void* up,
    const float* __restrict__ c1, const float* __restrict__ c2,
    const float* __restrict__ c3, const float* __restrict__ c4,
    const float* __restrict__ qn,
    const float* __restrict__ W1, const float* __restrict__ b1,
    const float* __restrict__ W2, const float* __restrict__ b2,
    const float* __restrict__ gamma, const float* __restrict__ beta,
    float* out)
{
    extern __shared__ char smem[];
    unsigned short* sW1 = (unsigned short*)(smem + OFF_W1);
    unsigned short* sW2 = (unsigned short*)(smem + OFF_W2);
    unsigned short* sX  = (unsigned short*)(smem + OFF_X);
    unsigned short* sH  = (unsigned short*)(smem + OFF_H);
    float2* red = (float2*)(smem + OFF_RED);

    const int tid = threadIdx.x;

    // ---- stage transposed bf16 weights once per block ----
    for (int c = tid; c < 36 * 128; c += THREADS) {
        int kb = c >> 7, n = c & 127;
        unsigned short tmp[8] __attribute__((aligned(16)));
        #pragma unroll
        for (int j = 0; j < 8; ++j) {
            int k = kb * 8 + j;
            tmp[j] = (k < 261) ? f2bf(W1[k * DD + n]) : (unsigned short)0;
        }
        *(uint4*)(sW1 + c * 8) = *(const uint4*)tmp;
    }
    for (int c = tid; c < 16 * 128; c += THREADS) {
        int kb = c >> 7, n = c & 127;
        unsigned short tmp[8] __attribute__((aligned(16)));
        #pragma unroll
        for (int j = 0; j < 8; ++j) tmp[j] = f2bf(W2[(kb * 8 + j) * DD + n]);
        *(uint4*)(sW2 + c * 8) = *(const uint4*)tmp;
    }
    // zero pad rows kb 33..35 once (never overwritten)
    if (tid < 192) {
        int kb = 33 + (tid >> 6), row = tid & 63;
        stx(sX, kb, row, make_uint4(0u, 0u, 0u, 0u));
    }

    const int lane = tid & 63;
    const int w    = tid >> 6;
    const int wm   = w >> 2;
    const int wn   = w & 3;
    const int l15  = lane & 15;
    const int lk   = lane >> 4;
    const int col0 = wn * 32 + l15;
    const int col1 = col0 + 16;

    const float b1v[2] = {b1[col0], b1[col1]};
    const float b2v[2] = {b2[col0], b2[col1]};
    const float gv[2]  = {gamma[col0], gamma[col1]};
    const float bv[2]  = {beta[col0], beta[col1]};

    const bf16x8* W1f = (const bf16x8*)sW1;
    const bf16x8* Hf  = (const bf16x8*)sH;
    const bf16x8* W2f = (const bf16x8*)sW2;

    // chunk coords (loop-invariant): thread owns (k0, r0) and (k0, r0+32)
    const int k0 = tid & 15;
    const int r0 = tid >> 4;          // 0..31

    // prefetch registers
    float4 h0a, h0b, h1a, h1b;
    uint4  u0, u1;                    // GATHER=1
    float4 v0a, v0b, v1a, v1b;        // GATHER=0
    float pc1 = 0.f, pc2 = 0.f, pc3 = 0.f, pc4 = 0.f, pc5 = 0.f;

    // ---- prologue prefetch: tile 0 ----
    {
        int base = blockIdx.x * TPB * TILE_M;
        const float* hp = h + (size_t)(base + r0) * DD + k0 * 8;
        h0a = *(const float4*)hp;       h0b = *(const float4*)(hp + 4);
        h1a = *(const float4*)(hp + 32 * DD); h1b = *(const float4*)(hp + 32 * DD + 4);
        if (GATHER) {
            const char* ub = (const char*)up;
            u0 = *(const uint4*)(ub + (size_t)(base + r0) * 512 + k0 * 16);
            u1 = *(const uint4*)(ub + (size_t)(base + r0 + 32) * 512 + k0 * 16);
        } else {
            const float* uf = (const float*)up + (size_t)(base + r0) * DD + k0 * 8;
            v0a = *(const float4*)uf;       v0b = *(const float4*)(uf + 4);
            v1a = *(const float4*)(uf + 32 * DD); v1b = *(const float4*)(uf + 32 * DD + 4);
        }
        if (tid < 64) {
            int n0 = base + tid;
            pc1 = c1[n0]; pc2 = c2[n0]; pc3 = c3[n0]; pc4 = c4[n0]; pc5 = qn[n0];
        }
    }
    __syncthreads();

    for (int tt = 0; tt < TPB; ++tt) {
        const int base = (blockIdx.x * TPB + tt) * TILE_M;

        // ---- write prefetched regs -> sX ----
        stx(sX, k0, r0,      pack8(h0a, h0b));
        stx(sX, k0, r0 + 32, pack8(h1a, h1b));
        if (GATHER) {
            stx(sX, 16 + k0, r0,      u0);
            stx(sX, 16 + k0, r0 + 32, u1);
        } else {
            stx(sX, 16 + k0, r0,      pack8(v0a, v0b));
            stx(sX, 16 + k0, r0 + 32, pack8(v1a, v1b));
        }
        if (tid < 64) {
            uint4 pv = make_uint4(pack2(signed_log(pc1), signed_log(pc2)),
                                  pack2(signed_log(pc3), signed_log(pc4)),
                                  pack2(signed_log(pc5), 0.f), 0u);
            stx(sX, 32, tid, pv);
        }

        // ---- issue prefetch for next tile (overlaps GEMM + epilogue) ----
        if (tt + 1 < TPB) {
            int bn = base + TILE_M;
            const float* hp = h + (size_t)(bn + r0) * DD + k0 * 8;
            h0a = *(const float4*)hp;       h0b = *(const float4*)(hp + 4);
            h1a = *(const float4*)(hp + 32 * DD); h1b = *(const float4*)(hp + 32 * DD + 4);
            if (GATHER) {
                const char* ub = (const char*)up;
                u0 = *(const uint4*)(ub + (size_t)(bn + r0) * 512 + k0 * 16);
                u1 = *(const uint4*)(ub + (size_t)(bn + r0 + 32) * 512 + k0 * 16);
            } else {
                const float* uf = (const float*)up + (size_t)(bn + r0) * DD + k0 * 8;
                v0a = *(const float4*)uf;       v0b = *(const float4*)(uf + 4);
                v1a = *(const float4*)(uf + 32 * DD); v1b = *(const float4*)(uf + 32 * DD + 4);
            }
            if (tid < 64) {
                int n0 = bn + tid;
                pc1 = c1[n0]; pc2 = c2[n0]; pc3 = c3[n0]; pc4 = c4[n0]; pc5 = qn[n0];
            }
        }
        __syncthreads();   // sX ready

        // ---- GEMM1: (64x288) @ (288x128) ----
        f32x4 acc[2][2] = {};
        #pragma unroll
        for (int ks = 0; ks < 9; ++ks) {
            int kb = ks * 4 + lk;
            bf16x8 a0  = ldx(sX, kb, wm * 32 + l15);
            bf16x8 a1  = ldx(sX, kb, wm * 32 + 16 + l15);
            bf16x8 bb0 = W1f[kb * 128 + col0];
            bf16x8 bb1 = W1f[kb * 128 + col1];
            acc[0][0] = __builtin_amdgcn_mfma_f32_16x16x32_bf16(a0, bb0, acc[0][0], 0, 0, 0);
            acc[0][1] = __builtin_amdgcn_mfma_f32_16x16x32_bf16(a0, bb1, acc[0][1], 0, 0, 0);
            acc[1][0] = __builtin_amdgcn_mfma_f32_16x16x32_bf16(a1, bb0, acc[1][0], 0, 0, 0);
            acc[1][1] = __builtin_amdgcn_mfma_f32_16x16x32_bf16(a1, bb1, acc[1][1], 0, 0, 0);
        }
        // silu -> hid tile
        #pragma unroll
        for (int fm = 0; fm < 2; ++fm) {
            int row = wm * 32 + fm * 16 + lk * 4;
            #pragma unroll
            for (int fn = 0; fn < 2; ++fn) {
                int col = wn * 32 + fn * 16 + l15;
                int kbh = col >> 3, ko = col & 7;
                #pragma unroll
                for (int r = 0; r < 4; ++r) {
                    float v = acc[fm][fn][r] + b1v[fn];
                    float sg = 1.f / (1.f + __expf(-v));
                    sH[(kbh * 64 + row + r) * 8 + ko] = f2bf(v * sg);
                }
            }
        }
        __syncthreads();

        // ---- GEMM2: (64x128) @ (128x128) ----
        f32x4 acc2[2][2] = {};
        #pragma unroll
        for (int ks = 0; ks < 4; ++ks) {
            int kb = ks * 4 + lk;
            bf16x8 a0  = Hf[kb * 64 + wm * 32 + l15];
            bf16x8 a1  = Hf[kb * 64 + wm * 32 + 16 + l15];
            bf16x8 bb0 = W2f[kb * 128 + col0];
            bf16x8 bb1 = W2f[kb * 128 + col1];
            acc2[0][0] = __builtin_amdgcn_mfma_f32_16x16x32_bf16(a0, bb0, acc2[0][0], 0, 0, 0);
            acc2[0][1] = __builtin_amdgcn_mfma_f32_16x16x32_bf16(a0, bb1, acc2[0][1], 0, 0, 0);
            acc2[1][0] = __builtin_amdgcn_mfma_f32_16x16x32_bf16(a1, bb0, acc2[1][0], 0, 0, 0);
            acc2[1][1] = __builtin_amdgcn_mfma_f32_16x16x32_bf16(a1, bb1, acc2[1][1], 0, 0, 0);
        }

        // ---- residual + LN partials ----
        float rs1[2][4], rs2[2][4];
        #pragma unroll
        for (int fm = 0; fm < 2; ++fm) {
            #pragma unroll
            for (int r = 0; r < 4; ++r) {
                size_t rowg = (size_t)(base + wm * 32 + fm * 16 + lk * 4 + r) * DD;
                float z0 = acc2[fm][0][r] + b2v[0] + h[rowg + col0];
                float z1 = acc2[fm][1][r] + b2v[1] + h[rowg + col1];
                acc2[fm][0][r] = z0; acc2[fm][1][r] = z1;
                float s = z0 + z1, q = z0 * z0 + z1 * z1;
                #pragma unroll
                for (int off = 1; off < 16; off <<= 1) {
                    s += __shfl_xor(s, off);
                    q += __shfl_xor(q, off);
                }
                rs1[fm][r] = s; rs2[fm][r] = q;
            }
        }
        if (l15 == 0) {
            #pragma unroll
            for (int fm = 0; fm < 2; ++fm)
                #pragma unroll
                for (int r = 0; r < 4; ++r)
                    red[wn * 64 + wm * 32 + fm * 16 + lk * 4 + r] =
                        make_float2(rs1[fm][r], rs2[fm][r]);
        }
        __syncthreads();

        #pragma unroll
        for (int fm = 0; fm < 2; ++fm) {
            #pragma unroll
            for (int r = 0; r < 4; ++r) {
                int rloc = wm * 32 + fm * 16 + lk * 4 + r;
                float2 t0 = red[rloc], t1 = red[64 + rloc],
                       t2 = red[128 + rloc], t3 = red[192 + rloc];
                float S = t0.x + t1.x + t2.x + t3.x;
                float Q = t0.y + t1.y + t2.y + t3.y;
                float mean = S * (1.f / 128.f);
                float var  = Q * (1.f / 128.f) - mean * mean;
                float rstd = rsqrtf(var + EPS_LN);
                size_t rowg = (size_t)(base + rloc) * DD;
                out[rowg + col0] = (acc2[fm][0][r] - mean) * rstd * gv[0] + bv[0];
                out[rowg + col1] = (acc2[fm][1][r] - mean) * rstd * gv[1] + bv[1];
            }
        }
        // loop back: sX rewrite is 2+ barriers after last sX read -> safe
    }
}

extern "C" void kernel_launch(void* const* d_in, const int* in_sizes, int n_in,
                              void* d_out, int out_size, void* d_ws, size_t ws_size,
                              hipStream_t stream) {
    const float* h     = (const float*)d_in[0];
    const float* c1    = (const float*)d_in[1];
    const float* c2    = (const float*)d_in[2];
    const float* c3    = (const float*)d_in[3];
    const float* c4    = (const float*)d_in[4];
    const float* qn    = (const float*)d_in[5];
    const int*   src   = (const int*)d_in[6];
    const int*   dst   = (const int*)d_in[7];
    const float* W1    = (const float*)d_in[8];
    const float* b1    = (const float*)d_in[9];
    const float* W2    = (const float*)d_in[10];
    const float* b2    = (const float*)d_in[11];
    const float* gamma = (const float*)d_in[12];
    const float* beta  = (const float*)d_in[13];
    float* out = (float*)d_out;
    int E = in_sizes[6];

    if (ws_size >= (size_t)WS_NEEDED) {
        char* ws = (char*)d_ws;
        int* offs   = (int*)(ws + WS_OFFS);
        int* cursor = (int*)(ws + WS_CURSOR);
        int* bsum   = (int*)(ws + WS_BSUM);
        int* esrc   = (int*)(ws + WS_ESRC);

        hipMemsetAsync(offs, 0, (size_t)NN * sizeof(int), stream);
        int eb = (E + 255) / 256;
        hist_kernel<<<eb, 256, 0, stream>>>(dst, offs, E);
        scan_local<<<NN / 256, 256, 0, stream>>>(offs, bsum);
        scan_bsum<<<1, 1024, 0, stream>>>(bsum);
        scan_fixup<<<NN / 256, 256, 0, stream>>>(offs, bsum, cursor, E);
        fill_kernel<<<eb, 256, 0, stream>>>(src, dst, cursor, esrc, E);

        gather_kernel<<<2048, 256, 0, stream>>>((const float4*)h, offs, esrc, (char*)d_out);

        hipFuncSetAttribute(reinterpret_cast<const void*>(&node_kernel<1>),
                            hipFuncAttributeMaxDynamicSharedMemorySize, SMEM_TOT);
        node_kernel<1><<<NBLOCKS, THREADS, SMEM_TOT, stream>>>(
            h, d_out, c1, c2, c3, c4, qn,
            W1, b1, W2, b2, gamma, beta, out);
    } else {
        // fallback: atomic scatter into d_out (fp32 upstream)
        hipMemsetAsync(d_out, 0, (size_t)NN * DD * sizeof(float), stream);
        int sthreads = E * 32;
        int sblocks = (sthreads + 255) / 256;
        scatter_kernel<<<sblocks, 256, 0, stream>>>((const float4*)h, src, dst, out, E);
        hipFuncSetAttribute(reinterpret_cast<const void*>(&node_kernel<0>),
                            hipFuncAttributeMaxDynamicSharedMemorySize, SMEM_TOT);
        node_kernel<0><<<NBLOCKS, THREADS, SMEM_TOT, stream>>>(
            h, d_out, c1, c2, c3, c4, qn,
            W1, b1, W2, b2, gamma, beta, out);
    }
}